// Round 5
// baseline (1157.397 us; speedup 1.0000x reference)
//
#include <hip/hip_runtime.h>

typedef _Float16 half8 __attribute__((ext_vector_type(8)));
typedef _Float16 hv4 __attribute__((ext_vector_type(4)));
typedef float fv4 __attribute__((ext_vector_type(4)));

typedef __attribute__((address_space(3))) unsigned lds_u32;
typedef const __attribute__((address_space(1))) unsigned glb_u32;

// async global->LDS, 16B per lane; dst is wave-uniform base, HW adds lane*16B
__device__ __forceinline__ void gll16(const void* g, void* l) {
  __builtin_amdgcn_global_load_lds((glb_u32*)g, (lds_u32*)l, 16, 0, 0);
}

// ---------------------------------------------------------------- LayerNorm
__device__ __forceinline__ void ln_body(const float* __restrict__ in, const float* __restrict__ g,
                                        const float* __restrict__ bb, _Float16* __restrict__ out,
                                        int ncols, int row) {
  __shared__ float sm[8];
  int t = threadIdx.x;
  const float* rp = in + (size_t)row * ncols;
  int nv = ncols >> 10;
  fv4 v[2];
  float s1 = 0.f, s2 = 0.f;
#pragma unroll
  for (int c = 0; c < 2; ++c)
    if (c < nv) {
      v[c] = *(const fv4*)(rp + c * 1024 + t * 4);
#pragma unroll
      for (int j = 0; j < 4; ++j) { s1 += v[c][j]; s2 += v[c][j] * v[c][j]; }
    }
#pragma unroll
  for (int off = 32; off > 0; off >>= 1) { s1 += __shfl_xor(s1, off, 64); s2 += __shfl_xor(s2, off, 64); }
  int w = t >> 6;
  if ((t & 63) == 0) { sm[w] = s1; sm[4 + w] = s2; }
  __syncthreads();
  s1 = sm[0] + sm[1] + sm[2] + sm[3];
  s2 = sm[4] + sm[5] + sm[6] + sm[7];
  float inv = 1.0f / (float)ncols;
  float mu = s1 * inv;
  float var = s2 * inv - mu * mu;
  float rstd = rsqrtf(var + 1e-5f);
#pragma unroll
  for (int c = 0; c < 2; ++c)
    if (c < nv) {
      int col = c * 1024 + t * 4;
      fv4 gg = *(const fv4*)(g + col);
      fv4 bv = *(const fv4*)(bb + col);
      hv4 o;
#pragma unroll
      for (int j = 0; j < 4; ++j) o[j] = (_Float16)(((v[c][j] - mu) * rstd) * gg[j] + bv[j]);
      *(hv4*)(out + (size_t)row * ncols + col) = o;
    }
}

__global__ __launch_bounds__(256) void ln_all(const float* __restrict__ hid,
                                              const float* __restrict__ mem,
                                              const float* __restrict__ gs, const float* __restrict__ bs,
                                              const float* __restrict__ gm, const float* __restrict__ bm,
                                              _Float16* __restrict__ oh, _Float16* __restrict__ om) {
  int b = blockIdx.x;
  if (b < 2048) ln_body(hid, gs, bs, oh, 2048, b);
  else ln_body(mem, gm, bm, om, 1024, b - 2048);
}

// ---------------------------------------------------------------- merged fp32 -> fp16 casts
__global__ __launch_bounds__(256) void cast_all(const float* __restrict__ s0, _Float16* __restrict__ d0,
                                                const float* __restrict__ s1, _Float16* __restrict__ d1,
                                                const float* __restrict__ s2, _Float16* __restrict__ d2,
                                                const float* __restrict__ s3, _Float16* __restrict__ d3) {
  int b = blockIdx.x;
  const float* s;
  _Float16* d;
  int off;
  if (b < 2048) { s = s0; d = d0; off = b; }
  else if (b < 3072) { s = s1; d = d1; off = b - 2048; }
  else if (b < 4096) { s = s2; d = d2; off = b - 3072; }
  else { s = s3; d = d3; off = b - 4096; }
  int i = (off * 256 + threadIdx.x) << 2;
  fv4 f = *(const fv4*)(s + i);
  hv4 h;
#pragma unroll
  for (int j = 0; j < 4; ++j) h[j] = (_Float16)f[j];
  *(hv4*)(d + i) = h;
}

// ---------------------------------------------------------------- sum ns partials -> fp16
__global__ __launch_bounds__(256) void reduce_split(const float* __restrict__ parts, int ns,
                                                    long long stride,
                                                    _Float16* __restrict__ hi, int n) {
  int i = (blockIdx.x * 256 + threadIdx.x) << 2;
  if (i < n) {
    fv4 s = *(const fv4*)(parts + i);
    for (int j = 1; j < ns; ++j) {
      fv4 v = *(const fv4*)(parts + (size_t)j * stride + i);
      s += v;
    }
    hv4 h;
#pragma unroll
    for (int j = 0; j < 4; ++j) h[j] = (_Float16)s[j];
    *(hv4*)(hi + i) = h;
  }
}

// ---------------------------------------------------------------- fused Hopfield 3-step
// One block = 16 xi-rows of one (b,h); ALL 3 steps run in-kernel (head slices are
// independent across steps). 4 waves; each wave owns 512 slots.
// K/V stream through per-wave 3-slot LDS rings (12 KB/wave) via global_load_lds,
// depth-2 prefetch, counted s_waitcnt vmcnt(4) — no barriers in streaming loops.
// K tiles: chunk-XOR swizzle (gemm-proven, 2-way banks).
// V tiles: slot-half swizzle — source half (l&1)^((l>>3)&1), read hsr=(quad>>1)^((lr>>2)&1)
//   -> uniform 4 dwords/bank on the b64 reads (minimum possible; conflict-free).
// Step transition: cross-wave reduce in ring (barrier-protected), new xi -> nx LDS
// buffer (fp16, stride 136; aliased with entmax scratch), bx re-fragmented from nx.
__global__ __launch_bounds__(256) void fused_step3(const _Float16* __restrict__ xi,
                                                   const _Float16* __restrict__ kp,
                                                   const _Float16* __restrict__ vt,
                                                   const float* __restrict__ log_beta,
                                                   _Float16* __restrict__ xo) {
  __shared__ __align__(16) _Float16 ring[4 * 3 * 2048];  // 48 KB: 4 waves x 3 slots x 4KB
  __shared__ __align__(16) _Float16 nxbuf[16 * 136];     // 4.25 KB: new xi / entmax scratch
  float* red = (float*)nxbuf;    // entmax scratch (384 f32)
  float* red4 = (float*)ring;    // 32 KB out-reduce (aliased on rings)

  int t = threadIdx.x;
  int wv = t >> 6, l = t & 63;
  int lr = l & 15, quad = l >> 4;

  int id = blockIdx.x;
  int h = id & 7;          // h pinned to XCD: K/V panels stay in one L2
  int rbb = id >> 3;       // 0..127
  int b = rbb >> 6;
  int r0 = (rbb & 63) << 4;

  const _Float16* xiP = xi + ((size_t)(b * 1024 + r0)) * 1024 + h * 128;
  const _Float16* kP = kp + (size_t)h * 128;
  const _Float16* vP = vt + (size_t)h * 128 * 2048;
  int sbase = wv * 512;

  _Float16* ringW = &ring[wv * 6144];  // this wave's 3-slot ring

  float lb = log_beta[h];
  float a05 = 0.5f * __expf(lb);

  // xi fragments (B-operand): lane holds xi-row lr, dims c*32 + quad*8 .. +8
  half8 bx[4];
#pragma unroll
  for (int c = 0; c < 4; ++c)
    bx[c] = *(const half8*)(xiP + (size_t)lr * 1024 + c * 32 + quad * 8);
  asm volatile("s_waitcnt vmcnt(0)" ::: "memory");  // clean vmcnt before counted staging

  // staging lane roles
  int srl = l >> 2;                           // K: slot-in-16
  int scs = ((l & 3) ^ ((l >> 3) & 3)) << 3;  // K: chunk-XOR source offset
  int rsw = (lr >> 1) & 3;                    // K read-side XOR key
  int vsh = ((l & 1) ^ ((l >> 3) & 1)) * 8;   // V: swizzled source slot-half
  int hsr = ((quad >> 1) ^ ((lr >> 2) & 1));  // V read-side half select

  // K tile f: [4 g][16 slots][32 dims chunk-swizzled]; 4 gll16
  auto stageK = [&](int f) {
    const _Float16* src = kP + (size_t)(sbase + f * 16 + srl) * 1024 + scs;
    _Float16* dst = ringW + (f % 3) * 2048;
#pragma unroll
    for (int g = 0; g < 4; ++g) gll16(src + g * 32, dst + g * 512);
  };
  // V tile f: [4 g][32 dims][2 half-swizzled x 8 slots]; 4 gll16
  auto stageV = [&](int f) {
    const _Float16* src = vP + (size_t)(l >> 1) * 2048 + sbase + f * 16 + vsh;
    _Float16* dst = ringW + (f % 3) * 2048;
#pragma unroll
    for (int g = 0; g < 4; ++g) gll16(src + (size_t)g * 32 * 2048, dst + g * 512);
  };

#pragma unroll 1
  for (int step = 0; step < 3; ++step) {
    // ---- phase 1: scores^T through the K ring
    fv4 sc[32];
    stageK(0); stageK(1);
#pragma unroll
    for (int f = 0; f < 32; ++f) {
      if (f < 31) asm volatile("s_waitcnt vmcnt(4)" ::: "memory");
      else asm volatile("s_waitcnt vmcnt(0)" ::: "memory");
      __builtin_amdgcn_sched_barrier(0);
      const _Float16* kb = ringW + (f % 3) * 2048;
      half8 ka[4];
#pragma unroll
      for (int g = 0; g < 4; ++g)
        ka[g] = *(const half8*)(kb + g * 512 + lr * 32 + ((quad ^ rsw) << 3));
      if (f + 2 < 32) stageK(f + 2);
      fv4 a = {0.f, 0.f, 0.f, 0.f};
      __builtin_amdgcn_s_setprio(1);
#pragma unroll
      for (int g = 0; g < 4; ++g)
        a = __builtin_amdgcn_mfma_f32_16x16x32_f16(ka[g], bx[g], a, 0, 0, 0);
      __builtin_amdgcn_s_setprio(0);
      sc[f] = a;
    }

    // ---- phase 2: row max, x = (beta*s - beta*max)/2, Michelot tau iteration
    float m = sc[0][0];
#pragma unroll
    for (int f = 0; f < 32; ++f)
#pragma unroll
      for (int r = 0; r < 4; ++r) m = fmaxf(m, sc[f][r]);
    m = fmaxf(m, __shfl_xor(m, 16, 64));
    m = fmaxf(m, __shfl_xor(m, 32, 64));
    __syncthreads();  // all waves past bx use of nxbuf / done with ring reads
    if (l < 16) red[wv * 48 + l] = m;
    __syncthreads();
    m = fmaxf(fmaxf(red[lr], red[48 + lr]), fmaxf(red[96 + lr], red[144 + lr]));

    float nc = -a05 * m;
#pragma unroll
    for (int f = 0; f < 32; ++f)
#pragma unroll
      for (int r = 0; r < 4; ++r) sc[f][r] = fmaf(a05, sc[f][r], nc);

    float tau = -1.0f;
    int par = 1;
#pragma unroll 1
    for (int it = 0; it < 20; ++it) {
      float cf = 0.f, s1 = 0.f, s2 = 0.f;
#pragma unroll
      for (int f = 0; f < 32; ++f)
#pragma unroll
        for (int r = 0; r < 4; ++r) {
          float v = sc[f][r];
          bool pb = v > tau;
          float sel = pb ? v : 0.f;
          cf += pb ? 1.f : 0.f;
          s1 += sel;
          s2 = fmaf(sel, sel, s2);
        }
      cf += __shfl_xor(cf, 16, 64); cf += __shfl_xor(cf, 32, 64);
      s1 += __shfl_xor(s1, 16, 64); s1 += __shfl_xor(s1, 32, 64);
      s2 += __shfl_xor(s2, 16, 64); s2 += __shfl_xor(s2, 32, 64);
      float* wr = red + par * 192 + wv * 48;
      if (l < 16) { wr[l] = cf; wr[16 + l] = s1; wr[32 + l] = s2; }
      __syncthreads();
      float C = 0.f, S1 = 0.f, S2 = 0.f;
#pragma unroll
      for (int w2 = 0; w2 < 4; ++w2) {
        const float* rr = red + par * 192 + w2 * 48;
        C += rr[lr]; S1 += rr[16 + lr]; S2 += rr[32 + lr];
      }
      par ^= 1;
      float mean = S1 / C;
      float ssv = S2 - S1 * mean;
      float nt = mean - sqrtf(fmaxf((1.0f - ssv) / C, 0.0f));
      bool conv = (nt == tau);  // identical across waves (row-dependent only)
      tau = nt;
      if (__all(conv)) break;
    }

    // ---- phase 3: w -> fp16 A-frags in registers (16x16x16 layout = sc layout)
    hv4 aw[32];
#pragma unroll
    for (int f = 0; f < 32; ++f) {
#pragma unroll
      for (int r = 0; r < 4; ++r) {
        float d = fmaxf(sc[f][r] - tau, 0.f);
        aw[f][r] = (_Float16)(d * d);
      }
    }

    // ---- phase 4: partial out[16 rows][128 dims] over this wave's 512 slots
    fv4 acc[8] = {};
    stageV(0); stageV(1);
#pragma unroll
    for (int f = 0; f < 32; ++f) {
      if (f < 31) asm volatile("s_waitcnt vmcnt(4)" ::: "memory");
      else asm volatile("s_waitcnt vmcnt(0)" ::: "memory");
      __builtin_amdgcn_sched_barrier(0);
      const _Float16* vb = ringW + (f % 3) * 2048;
      hv4 bv[8];
#pragma unroll
      for (int ni = 0; ni < 8; ++ni)
        bv[ni] = *(const hv4*)(vb + (ni >> 1) * 512 + ((ni & 1) * 16 + lr) * 16 + hsr * 8 + (quad & 1) * 4);
      if (f + 2 < 32) stageV(f + 2);
      __builtin_amdgcn_s_setprio(1);
#pragma unroll
      for (int ni = 0; ni < 8; ++ni)
        acc[ni] = __builtin_amdgcn_mfma_f32_16x16x16f16(aw[f], bv[ni], acc[ni], 0, 0, 0);
      __builtin_amdgcn_s_setprio(0);
    }

    // ---- cross-wave reduce (red4 aliases rings: barrier both sides)
    __syncthreads();
#pragma unroll
    for (int ni = 0; ni < 8; ++ni)
#pragma unroll
      for (int r = 0; r < 4; ++r)
        red4[wv * 2048 + (quad * 4 + r) * 128 + ni * 16 + lr] = acc[ni][r];
    __syncthreads();
#pragma unroll
    for (int g = 0; g < 2; ++g) {
      int idx = wv * 512 + g * 256 + l * 4;
      fv4 s = *(const fv4*)&red4[idx];
      s += *(const fv4*)&red4[idx + 2048];
      s += *(const fv4*)&red4[idx + 4096];
      s += *(const fv4*)&red4[idx + 6144];
      int row = idx >> 7, dim = idx & 127;
      hv4 o;
#pragma unroll
      for (int j = 0; j < 4; ++j) o[j] = (_Float16)s[j];
      *(hv4*)&nxbuf[row * 136 + dim] = o;
      if (step == 2)
        *(hv4*)(xo + ((size_t)(b * 1024 + r0 + row)) * 1024 + h * 128 + dim) = o;
    }
    __syncthreads();
    if (step < 2) {
      // re-fragment bx from the new xi
#pragma unroll
      for (int c = 0; c < 4; ++c)
        bx[c] = *(const half8*)&nxbuf[lr * 136 + c * 32 + quad * 8];
      // next step's ring writes / nxbuf scratch use are fenced by the phase-2 barrier
    }
  }
}

// ---------------------------------------------------------------- generic NT GEMM
// C[M,N] = A[M,K] @ B[N,K]^T.  128x128 tile, 4 waves, 4x4 16x16x32 f16 MFMA.
// 3-buffer LDS pipeline, prefetch depth 2, counted s_waitcnt vmcnt(4) + raw s_barrier.
struct GemmParams {
  const _Float16 *A, *B, *B2;
  _Float16 *C16, *C16b;
  float* C32;
  int K, lda, ldb;
  long long aSB, aSH, bSH;
  long long cSB, cSH, cOsR, cOsC;
  long long cOsRb, cOsCb;
  long long partStride;
  int outMode, outModeB, nsplit, dual;
  int gx, gy, swz;
};

__device__ __forceinline__ void gemm_body(const GemmParams& p, int bx, int by, int bz) {
  __shared__ __align__(16) _Float16 As[3][128 * 32];
  __shared__ __align__(16) _Float16 Bs[3][128 * 32];
  int t = threadIdx.x;
  int m0 = by * 128;
  int n0, kbeg, kend, ks = 0;
  if (p.nsplit > 1) {
    ks = bx % p.nsplit;
    n0 = (bx / p.nsplit) * 128;
    int kl = p.K / p.nsplit;
    kbeg = ks * kl;
    kend = kbeg + kl;
  } else {
    n0 = bx * 128;
    kbeg = 0;
    kend = p.K;
  }
  int bidx, h, job = 0;
  if (p.dual) { job = bz; bidx = 0; h = 0; }
  else { bidx = bz >> 3; h = bz & 7; }
  const _Float16* pA = p.A + bidx * p.aSB + h * p.aSH;
  const _Float16* pB = (job ? p.B2 : p.B) + h * p.bSH;

  fv4 acc[4][4] = {};
  int wv = t >> 6, l = t & 63, quad = l >> 4, lr = l & 15;
  int wm = (wv >> 1) * 64, wn = (wv & 1) * 64;
  int rl = l >> 2;
  int cs = (((l & 3) ^ ((l >> 3) & 3)) << 3);
  int rsw = (lr >> 1) & 3;

  auto STAGE = [&](int buf, int k0) {
#pragma unroll
    for (int v = 0; v < 2; ++v) {
      int rb = wv * 16 + v * 64;
      int r = rb + rl;
      gll16(pA + (size_t)(m0 + r) * p.lda + k0 + cs, &As[buf][rb * 32]);
      gll16(pB + (size_t)(n0 + r) * p.ldb + k0 + cs, &Bs[buf][rb * 32]);
    }
  };

  int nk = (kend - kbeg) >> 5;
  STAGE(0, kbeg);
  if (nk > 1) STAGE(1, kbeg + 32);
  int cur = 0;
  for (int ti = 0; ti < nk; ++ti) {
    if (ti + 1 < nk) asm volatile("s_waitcnt vmcnt(4)" ::: "memory");
    else asm volatile("s_waitcnt vmcnt(0)" ::: "memory");
    __builtin_amdgcn_s_barrier();
    __builtin_amdgcn_sched_barrier(0);
    if (ti + 2 < nk) {
      int nb = cur + 2;
      if (nb >= 3) nb -= 3;
      STAGE(nb, kbeg + ((ti + 2) << 5));
    }
    __builtin_amdgcn_sched_barrier(0);
    half8 ah[4], bh[4];
#pragma unroll
    for (int mi = 0; mi < 4; ++mi)
      ah[mi] = *(const half8*)&As[cur][(wm + mi * 16 + lr) * 32 + ((quad ^ rsw) << 3)];
#pragma unroll
    for (int ni = 0; ni < 4; ++ni)
      bh[ni] = *(const half8*)&Bs[cur][(wn + ni * 16 + lr) * 32 + ((quad ^ rsw) << 3)];
    __builtin_amdgcn_s_setprio(1);
#pragma unroll
    for (int mi = 0; mi < 4; ++mi)
#pragma unroll
      for (int ni = 0; ni < 4; ++ni)
        acc[mi][ni] = __builtin_amdgcn_mfma_f32_16x16x32_f16(ah[mi], bh[ni], acc[mi][ni], 0, 0, 0);
    __builtin_amdgcn_s_setprio(0);
    cur = (cur == 2) ? 0 : cur + 1;
  }

  int om = (p.dual && job) ? p.outModeB : p.outMode;
  _Float16* c16 = (p.dual && job) ? p.C16b : p.C16;
  long long osR = (p.dual && job) ? p.cOsRb : p.cOsR;
  long long osC = (p.dual && job) ? p.cOsCb : p.cOsC;
  float* c32 = p.C32 + (p.nsplit > 1 ? (long long)ks * p.partStride : 0);
  long long cOff = (long long)bidx * p.cSB + (long long)h * p.cSH;
#pragma unroll
  for (int mi = 0; mi < 4; ++mi)
#pragma unroll
    for (int ni = 0; ni < 4; ++ni) {
      int row = m0 + wm + mi * 16 + quad * 4;
      int col = n0 + wn + ni * 16 + lr;
#pragma unroll
      for (int r = 0; r < 4; ++r) {
        float val = acc[mi][ni][r];
        long long idx = cOff + (long long)(row + r) * osR + (long long)col * osC;
        if (om == 1) c32[idx] = val;
        else c16[idx] = (_Float16)val;
      }
    }
}

__global__ __launch_bounds__(256) void gemm_nt(GemmParams p) {
  int id = blockIdx.x;
  if (p.swz) {
    int q = (int)gridDim.x >> 3;
    id = (id & 7) * q + (id >> 3);
  }
  int bx = id % p.gx;
  int r = id / p.gx;
  gemm_body(p, bx, r % p.gy, r / p.gy);
}

__global__ __launch_bounds__(256) void gemm_pair(GemmParams a, GemmParams b, int na) {
  int id = blockIdx.x;
  if (id < na) {
    int bx = id % a.gx;
    int r = id / a.gx;
    gemm_body(a, bx, r % a.gy, r / a.gy);
  } else {
    int j = id - na;
    int bx = j % b.gx;
    int r = j / b.gx;
    gemm_body(b, bx, r % b.gy, r / b.gy);
  }
}

// ---------------------------------------------------------------- host
extern "C" void kernel_launch(void* const* d_in, const int* in_sizes, int n_in,
                              void* d_out, int out_size, void* d_ws, size_t ws_size,
                              hipStream_t stream) {
  const float* hidden = (const float*)d_in[0];   // (2,1024,2048)
  const float* memory = (const float*)d_in[1];   // (2048,1024)
  const float* Wq = (const float*)d_in[2];       // (1024,2048)
  const float* Wk = (const float*)d_in[3];       // (1024,1024)
  const float* Wv = (const float*)d_in[4];       // (1024,1024)
  const float* Wo = (const float*)d_in[5];       // (2048,1024)
  const float* log_beta = (const float*)d_in[6]; // (8,)
  const float* g_state = (const float*)d_in[7];
  const float* b_state = (const float*)d_in[8];
  const float* g_mem = (const float*)d_in[9];
  const float* b_mem = (const float*)d_in[10];

  char* w = (char*)d_ws;
  auto alloc = [&](size_t bytes) {
    char* r = w;
    w += (bytes + 255) & ~(size_t)255;
    return r;
  };
  _Float16* wq16 = (_Float16*)alloc(2097152 * 2);
  _Float16* wk16 = (_Float16*)alloc(1048576 * 2);
  _Float16* wv16 = (_Float16*)alloc(1048576 * 2);
  _Float16* wo16 = (_Float16*)alloc(2097152 * 2);
  _Float16* lnh16 = (_Float16*)alloc(4194304 * 2);
  _Float16* mn16 = (_Float16*)alloc(2097152 * 2);
  _Float16* kph = (_Float16*)alloc(2097152 * 2);   // K proj (n, h*128+d)
  _Float16* vt16 = (_Float16*)alloc(2097152 * 2);  // V^T (h*128+d, n)
  _Float16* xih = (_Float16*)alloc(2097152 * 2);   // xi (b*S+s, h*128+d)
  float* parts = (float*)alloc((size_t)2 * 2097152 * 4);  // Q split-K partials

  ln_all<<<4096, 256, 0, stream>>>(hidden, memory, g_state, b_state, g_mem, b_mem, lnh16, mn16);
  cast_all<<<6144, 256, 0, stream>>>(Wq, wq16, Wk, wk16, Wv, wv16, Wo, wo16);

  // Q = ln(hidden) @ Wq^T (split-K=2) + K/V projections (dual) in ONE launch
  {
    GemmParams pq{};
    pq.A = lnh16; pq.lda = 2048;
    pq.B = wq16; pq.ldb = 2048;
    pq.K = 2048; pq.nsplit = 2;
    pq.C32 = parts; pq.outMode = 1; pq.partStride = 2097152;
    pq.cOsR = 1024; pq.cOsC = 1;
    pq.gx = 16; pq.gy = 16;  // 256 blocks

    GemmParams pkv{};
    pkv.A = mn16; pkv.lda = 1024;
    pkv.B = wk16; pkv.B2 = wv16; pkv.ldb = 1024;
    pkv.K = 1024; pkv.dual = 1;
    pkv.C16 = kph; pkv.outMode = 0; pkv.cOsR = 1024; pkv.cOsC = 1;
    pkv.C16b = vt16; pkv.outModeB = 0; pkv.cOsRb = 1; pkv.cOsCb = 2048;
    pkv.gx = 8; pkv.gy = 16;  // gz=2 -> 256 blocks

    gemm_pair<<<512, 256, 0, stream>>>(pq, pkv, 256);
    reduce_split<<<2048, 256, 0, stream>>>(parts, 2, 2097152, xih, 2097152);
  }

  // 3 Hopfield steps in ONE launch (head slices independent across steps)
  fused_step3<<<1024, 256, 0, stream>>>(xih, kph, vt16, log_beta, xih);

  // out = xi @ Wo^T  (fp32 out)
  {
    GemmParams p{};
    p.A = xih; p.lda = 1024;
    p.B = wo16; p.ldb = 1024;
    p.K = 1024;
    p.C32 = (float*)d_out; p.outMode = 1;
    p.cOsR = 2048; p.cOsC = 1;
    p.gx = 16; p.gy = 16; p.swz = 1;  // 256 blocks
    gemm_nt<<<256, 256, 0, stream>>>(p);
  }
}

// Round 7
// 489.404 us; speedup vs baseline: 2.3649x; 2.3649x over previous
//
#include <hip/hip_runtime.h>

typedef _Float16 half8 __attribute__((ext_vector_type(8)));
typedef _Float16 hv4 __attribute__((ext_vector_type(4)));
typedef _Float16 h2 __attribute__((ext_vector_type(2)));
typedef float fv4 __attribute__((ext_vector_type(4)));

typedef __attribute__((address_space(3))) unsigned lds_u32;
typedef const __attribute__((address_space(1))) unsigned glb_u32;

#if defined(__has_builtin)
#if __has_builtin(__builtin_amdgcn_fdot2)
#define FDOT2(a, b, c) __builtin_amdgcn_fdot2((a), (b), (c), false)
#endif
#endif
#ifndef FDOT2
#define FDOT2(a, b, c) ((c) + (float)(a)[0] * (float)(b)[0] + (float)(a)[1] * (float)(b)[1])
#endif

// packed f32x2 -> fp16x2 (round-toward-zero); builtin returns __fp16x2, bit-cast to h2
__device__ __forceinline__ h2 pkrtz(float a, float b) {
  return __builtin_bit_cast(h2, __builtin_amdgcn_cvt_pkrtz(a, b));
}

// async global->LDS, 16B per lane; dst is wave-uniform base, HW adds lane*16B
__device__ __forceinline__ void gll16(const void* g, void* l) {
  __builtin_amdgcn_global_load_lds((glb_u32*)g, (lds_u32*)l, 16, 0, 0);
}

// ---------------------------------------------------------------- LayerNorm
__device__ __forceinline__ void ln_body(const float* __restrict__ in, const float* __restrict__ g,
                                        const float* __restrict__ bb, _Float16* __restrict__ out,
                                        int ncols, int row) {
  __shared__ float sm[8];
  int t = threadIdx.x;
  const float* rp = in + (size_t)row * ncols;
  int nv = ncols >> 10;
  fv4 v[2];
  float s1 = 0.f, s2 = 0.f;
#pragma unroll
  for (int c = 0; c < 2; ++c)
    if (c < nv) {
      v[c] = *(const fv4*)(rp + c * 1024 + t * 4);
#pragma unroll
      for (int j = 0; j < 4; ++j) { s1 += v[c][j]; s2 += v[c][j] * v[c][j]; }
    }
#pragma unroll
  for (int off = 32; off > 0; off >>= 1) { s1 += __shfl_xor(s1, off, 64); s2 += __shfl_xor(s2, off, 64); }
  int w = t >> 6;
  if ((t & 63) == 0) { sm[w] = s1; sm[4 + w] = s2; }
  __syncthreads();
  s1 = sm[0] + sm[1] + sm[2] + sm[3];
  s2 = sm[4] + sm[5] + sm[6] + sm[7];
  float inv = 1.0f / (float)ncols;
  float mu = s1 * inv;
  float var = s2 * inv - mu * mu;
  float rstd = rsqrtf(var + 1e-5f);
#pragma unroll
  for (int c = 0; c < 2; ++c)
    if (c < nv) {
      int col = c * 1024 + t * 4;
      fv4 gg = *(const fv4*)(g + col);
      fv4 bv = *(const fv4*)(bb + col);
      hv4 o;
#pragma unroll
      for (int j = 0; j < 4; ++j) o[j] = (_Float16)(((v[c][j] - mu) * rstd) * gg[j] + bv[j]);
      *(hv4*)(out + (size_t)row * ncols + col) = o;
    }
}

__global__ __launch_bounds__(256) void ln_all(const float* __restrict__ hid,
                                              const float* __restrict__ mem,
                                              const float* __restrict__ gs, const float* __restrict__ bs,
                                              const float* __restrict__ gm, const float* __restrict__ bm,
                                              _Float16* __restrict__ oh, _Float16* __restrict__ om) {
  int b = blockIdx.x;
  if (b < 2048) ln_body(hid, gs, bs, oh, 2048, b);
  else ln_body(mem, gm, bm, om, 1024, b - 2048);
}

// ---------------------------------------------------------------- merged fp32 -> fp16 casts
__global__ __launch_bounds__(256) void cast_all(const float* __restrict__ s0, _Float16* __restrict__ d0,
                                                const float* __restrict__ s1, _Float16* __restrict__ d1,
                                                const float* __restrict__ s2, _Float16* __restrict__ d2,
                                                const float* __restrict__ s3, _Float16* __restrict__ d3) {
  int b = blockIdx.x;
  const float* s;
  _Float16* d;
  int off;
  if (b < 2048) { s = s0; d = d0; off = b; }
  else if (b < 3072) { s = s1; d = d1; off = b - 2048; }
  else if (b < 4096) { s = s2; d = d2; off = b - 3072; }
  else { s = s3; d = d3; off = b - 4096; }
  int i = (off * 256 + threadIdx.x) << 2;
  fv4 f = *(const fv4*)(s + i);
  hv4 h;
#pragma unroll
  for (int j = 0; j < 4; ++j) h[j] = (_Float16)f[j];
  *(hv4*)(d + i) = h;
}

// ---------------------------------------------------------------- sum ns partials -> fp16
__global__ __launch_bounds__(256) void reduce_split(const float* __restrict__ parts, int ns,
                                                    long long stride,
                                                    _Float16* __restrict__ hi, int n) {
  int i = (blockIdx.x * 256 + threadIdx.x) << 2;
  if (i < n) {
    fv4 s = *(const fv4*)(parts + i);
    for (int j = 1; j < ns; ++j) {
      fv4 v = *(const fv4*)(parts + (size_t)j * stride + i);
      s += v;
    }
    hv4 h;
#pragma unroll
    for (int j = 0; j < 4; ++j) h[j] = (_Float16)s[j];
    *(hv4*)(hi + i) = h;
  }
}

// ---------------------------------------------------------------- fused Hopfield step v3
// One block = 16 xi-rows of one (b,h). 4 waves; each wave owns 512 slots.
// K/V stream through per-wave 3-slot LDS rings (12 KB/wave) via global_load_lds,
// depth-2 prefetch, counted s_waitcnt vmcnt(4) (wave-private rings, no barriers).
// Scores stored PACKED fp16 (h2 pk[64] = 64 VGPR, was fp32 sc[32] = 128): halves
// register pressure -> with 50.7 KB LDS and launch_bounds(256,3), 3 blocks/CU.
// Michelot iteration on packed fp16: y=pk_max(x,tau), M1=dot2(y,1), M2=dot2(y,y)
// (fp32 accum; exact algebra correction with quantized tau), support count via
// sign-bit trick on (tau_pk - y). Phase 3 overwrites pk in place with w=(x-tau)^2
// packed fp16 == the exact 16x16x16 A-frag layout (zero shuffles).
__global__ __launch_bounds__(256, 3) void fused_step(const _Float16* __restrict__ xi,
                                                     const _Float16* __restrict__ kp,
                                                     const _Float16* __restrict__ vt,
                                                     const float* __restrict__ log_beta,
                                                     _Float16* __restrict__ xo) {
  __shared__ __align__(16) _Float16 ring[4 * 3 * 2048];  // 48 KB: 4 waves x 3 slots x 4KB
  __shared__ float red[384];                             // entmax scratch (separate)
  float* red4 = (float*)ring;                            // 32 KB out-reduce (aliased)

  int t = threadIdx.x;
  int wv = t >> 6, l = t & 63;
  int lr = l & 15, quad = l >> 4;

  int id = blockIdx.x;
  int h = id & 7;          // h == XCD (default dispatch round-robins %8): K/V L2-pinned
  int rbb = id >> 3;       // 0..127
  int b = rbb >> 6;
  int r0 = (rbb & 63) << 4;

  const _Float16* xiP = xi + ((size_t)(b * 1024 + r0)) * 1024 + h * 128;
  const _Float16* kP = kp + (size_t)h * 128;
  const _Float16* vP = vt + (size_t)h * 128 * 2048;
  int sbase = wv * 512;

  _Float16* ringW = &ring[wv * 6144];  // this wave's 3-slot ring

  float a05 = 0.5f * __expf(log_beta[h]);

  // xi fragments (B-operand): lane holds xi-row lr, dims c*32 + quad*8 .. +8
  half8 bx[4];
#pragma unroll
  for (int c = 0; c < 4; ++c)
    bx[c] = *(const half8*)(xiP + (size_t)lr * 1024 + c * 32 + quad * 8);
  asm volatile("s_waitcnt vmcnt(0)" ::: "memory");  // clean vmcnt before counted staging

  // staging lane roles
  int srl = l >> 2;                           // K: slot-in-16
  int scs = ((l & 3) ^ ((l >> 3) & 3)) << 3;  // K: chunk-XOR source offset
  int rsw = (lr >> 1) & 3;                    // K read-side XOR key
  int vsh = ((l & 1) ^ ((l >> 3) & 1)) * 8;   // V: swizzled source slot-half
  int hsr = ((quad >> 1) ^ ((lr >> 2) & 1));  // V read-side half select

  auto stageK = [&](int f) {
    const _Float16* src = kP + (size_t)(sbase + f * 16 + srl) * 1024 + scs;
    _Float16* dst = ringW + (f % 3) * 2048;
#pragma unroll
    for (int g = 0; g < 4; ++g) gll16(src + g * 32, dst + g * 512);
  };
  auto stageV = [&](int f) {
    const _Float16* src = vP + (size_t)(l >> 1) * 2048 + sbase + f * 16 + vsh;
    _Float16* dst = ringW + (f % 3) * 2048;
#pragma unroll
    for (int g = 0; g < 4; ++g) gll16(src + (size_t)g * 32 * 2048, dst + g * 512);
  };

  // ---- phase 1: scores^T through the K ring -> packed fp16 (scaled by a05)
  h2 pk[64];
  float msc = -3.0e38f;
  stageK(0); stageK(1);
#pragma unroll
  for (int f = 0; f < 32; ++f) {
    if (f < 31) asm volatile("s_waitcnt vmcnt(4)" ::: "memory");
    else asm volatile("s_waitcnt vmcnt(0)" ::: "memory");
    __builtin_amdgcn_sched_barrier(0);
    const _Float16* kb = ringW + (f % 3) * 2048;
    half8 ka[4];
#pragma unroll
    for (int g = 0; g < 4; ++g)
      ka[g] = *(const half8*)(kb + g * 512 + lr * 32 + ((quad ^ rsw) << 3));
    if (f + 2 < 32) stageK(f + 2);
    fv4 a = {0.f, 0.f, 0.f, 0.f};
    __builtin_amdgcn_s_setprio(1);
#pragma unroll
    for (int g = 0; g < 4; ++g)
      a = __builtin_amdgcn_mfma_f32_16x16x32_f16(ka[g], bx[g], a, 0, 0, 0);
    __builtin_amdgcn_s_setprio(0);
    msc = fmaxf(fmaxf(msc, fmaxf(a[0], a[1])), fmaxf(a[2], a[3]));
    pk[2 * f] = pkrtz(a05 * a[0], a05 * a[1]);
    pk[2 * f + 1] = pkrtz(a05 * a[2], a05 * a[3]);
  }

  // ---- phase 2a: row max (fp32, cross-wave), normalize packed x -= m
  msc = fmaxf(msc, __shfl_xor(msc, 16, 64));
  msc = fmaxf(msc, __shfl_xor(msc, 32, 64));
  if (l < 16) red[wv * 48 + l] = msc;
  __syncthreads();
  msc = fmaxf(fmaxf(red[lr], red[48 + lr]), fmaxf(red[96 + lr], red[144 + lr]));
  float xm = a05 * msc;
  h2 mpk = {(_Float16)xm, (_Float16)xm};
#pragma unroll
  for (int p = 0; p < 64; ++p) pk[p] = pk[p] - mpk;

  // ---- phase 2b: Michelot tau iteration on packed fp16
  h2 one2 = {(_Float16)1.0f, (_Float16)1.0f};
  float tau = -1.0f;
  int par = 1;
#pragma unroll 1
  for (int it = 0; it < 14; ++it) {
    h2 tp = {(_Float16)tau, (_Float16)tau};
    float tq = (float)tp[0];  // quantized tau actually used by the clamps
    float M1 = 0.f, M2 = 0.f;
    unsigned kc = 0;
#pragma unroll
    for (int p = 0; p < 64; ++p) {
      h2 y = __builtin_elementwise_max(pk[p], tp);
      M1 = FDOT2(y, one2, M1);
      M2 = FDOT2(y, y, M2);
      h2 d = tp - y;  // sign bit set iff element in support
      unsigned u = __builtin_bit_cast(unsigned, d);
      kc += (u >> 15) & 0x10001u;
    }
    float kf = (float)((kc & 0xffffu) + (kc >> 16));
    kf += __shfl_xor(kf, 16, 64); kf += __shfl_xor(kf, 32, 64);
    M1 += __shfl_xor(M1, 16, 64); M1 += __shfl_xor(M1, 32, 64);
    M2 += __shfl_xor(M2, 16, 64); M2 += __shfl_xor(M2, 32, 64);
    float* wr = red + par * 192 + wv * 48;
    if (l < 16) { wr[l] = kf; wr[16 + l] = M1; wr[32 + l] = M2; }
    __syncthreads();
    float C = 0.f, S1 = 0.f, S2 = 0.f;
#pragma unroll
    for (int w2 = 0; w2 < 4; ++w2) {
      const float* rr = red + par * 192 + w2 * 48;
      C += rr[lr]; S1 += rr[16 + lr]; S2 += rr[32 + lr];
    }
    par ^= 1;
    // un-clamp: M-sums counted tau for the (2048-C) non-support elements
    S1 = S1 - (2048.0f - C) * tq;
    S2 = S2 - (2048.0f - C) * tq * tq;
    float mean = S1 / C;
    float ssv = S2 - S1 * mean;
    float nt = mean - sqrtf(fmaxf((1.0f - ssv) / C, 0.0f));
    bool conv = fabsf(nt - tau) < 1e-4f;  // identical across waves (row-dependent only)
    tau = nt;
    if (__all(conv)) break;
  }

  // ---- phase 3: w = (max(x - tau, 0))^2, packed fp16, in place (A-frag layout)
  {
    h2 tp = {(_Float16)tau, (_Float16)tau};
#pragma unroll
    for (int p = 0; p < 64; ++p) {
      h2 y = __builtin_elementwise_max(pk[p], tp);
      h2 d = y - tp;
      pk[p] = d * d;
    }
  }

  // ---- phase 4: partial out[16 rows][128 dims] over this wave's 512 slots
  fv4 acc[8] = {};
  stageV(0); stageV(1);
#pragma unroll
  for (int f = 0; f < 32; ++f) {
    if (f < 31) asm volatile("s_waitcnt vmcnt(4)" ::: "memory");
    else asm volatile("s_waitcnt vmcnt(0)" ::: "memory");
    __builtin_amdgcn_sched_barrier(0);
    const _Float16* vb = ringW + (f % 3) * 2048;
    hv4 bv[8];
#pragma unroll
    for (int ni = 0; ni < 8; ++ni)
      bv[ni] = *(const hv4*)(vb + (ni >> 1) * 512 + ((ni & 1) * 16 + lr) * 16 + hsr * 8 + (quad & 1) * 4);
    if (f + 2 < 32) stageV(f + 2);
    hv4 aw4 = {pk[2 * f][0], pk[2 * f][1], pk[2 * f + 1][0], pk[2 * f + 1][1]};
    __builtin_amdgcn_s_setprio(1);
#pragma unroll
    for (int ni = 0; ni < 8; ++ni)
      acc[ni] = __builtin_amdgcn_mfma_f32_16x16x16f16(aw4, bv[ni], acc[ni], 0, 0, 0);
    __builtin_amdgcn_s_setprio(0);
  }

  // ---- cross-wave reduce (red4 aliases rings: barrier both sides)
  __syncthreads();
#pragma unroll
  for (int ni = 0; ni < 8; ++ni)
#pragma unroll
    for (int r = 0; r < 4; ++r)
      red4[wv * 2048 + (quad * 4 + r) * 128 + ni * 16 + lr] = acc[ni][r];
  __syncthreads();
#pragma unroll
  for (int g = 0; g < 2; ++g) {
    int idx = wv * 512 + g * 256 + l * 4;
    fv4 s = *(const fv4*)&red4[idx];
    s += *(const fv4*)&red4[idx + 2048];
    s += *(const fv4*)&red4[idx + 4096];
    s += *(const fv4*)&red4[idx + 6144];
    int row = idx >> 7, dim = idx & 127;
    hv4 o;
#pragma unroll
    for (int j = 0; j < 4; ++j) o[j] = (_Float16)s[j];
    *(hv4*)(xo + ((size_t)(b * 1024 + r0 + row)) * 1024 + h * 128 + dim) = o;
  }
}

// ---------------------------------------------------------------- generic NT GEMM
// C[M,N] = A[M,K] @ B[N,K]^T.  128x128 tile, 4 waves, 4x4 16x16x32 f16 MFMA.
// 3-buffer LDS pipeline, prefetch depth 2, counted s_waitcnt vmcnt(4) + raw s_barrier.
struct GemmParams {
  const _Float16 *A, *B, *B2;
  _Float16 *C16, *C16b;
  float* C32;
  int K, lda, ldb;
  long long aSB, aSH, bSH;
  long long cSB, cSH, cOsR, cOsC;
  long long cOsRb, cOsCb;
  long long partStride;
  int outMode, outModeB, nsplit, dual;
  int gx, gy, swz;
};

__device__ __forceinline__ void gemm_body(const GemmParams& p, int bx, int by, int bz) {
  __shared__ __align__(16) _Float16 As[3][128 * 32];
  __shared__ __align__(16) _Float16 Bs[3][128 * 32];
  int t = threadIdx.x;
  int m0 = by * 128;
  int n0, kbeg, kend, ks = 0;
  if (p.nsplit > 1) {
    ks = bx % p.nsplit;
    n0 = (bx / p.nsplit) * 128;
    int kl = p.K / p.nsplit;
    kbeg = ks * kl;
    kend = kbeg + kl;
  } else {
    n0 = bx * 128;
    kbeg = 0;
    kend = p.K;
  }
  int bidx, h, job = 0;
  if (p.dual) { job = bz; bidx = 0; h = 0; }
  else { bidx = bz >> 3; h = bz & 7; }
  const _Float16* pA = p.A + bidx * p.aSB + h * p.aSH;
  const _Float16* pB = (job ? p.B2 : p.B) + h * p.bSH;

  fv4 acc[4][4] = {};
  int wv = t >> 6, l = t & 63, quad = l >> 4, lr = l & 15;
  int wm = (wv >> 1) * 64, wn = (wv & 1) * 64;
  int rl = l >> 2;
  int cs = (((l & 3) ^ ((l >> 3) & 3)) << 3);
  int rsw = (lr >> 1) & 3;

  auto STAGE = [&](int buf, int k0) {
#pragma unroll
    for (int v = 0; v < 2; ++v) {
      int rb = wv * 16 + v * 64;
      int r = rb + rl;
      gll16(pA + (size_t)(m0 + r) * p.lda + k0 + cs, &As[buf][rb * 32]);
      gll16(pB + (size_t)(n0 + r) * p.ldb + k0 + cs, &Bs[buf][rb * 32]);
    }
  };

  int nk = (kend - kbeg) >> 5;
  STAGE(0, kbeg);
  if (nk > 1) STAGE(1, kbeg + 32);
  int cur = 0;
  for (int ti = 0; ti < nk; ++ti) {
    if (ti + 1 < nk) asm volatile("s_waitcnt vmcnt(4)" ::: "memory");
    else asm volatile("s_waitcnt vmcnt(0)" ::: "memory");
    __builtin_amdgcn_s_barrier();
    __builtin_amdgcn_sched_barrier(0);
    if (ti + 2 < nk) {
      int nb = cur + 2;
      if (nb >= 3) nb -= 3;
      STAGE(nb, kbeg + ((ti + 2) << 5));
    }
    __builtin_amdgcn_sched_barrier(0);
    half8 ah[4], bh[4];
#pragma unroll
    for (int mi = 0; mi < 4; ++mi)
      ah[mi] = *(const half8*)&As[cur][(wm + mi * 16 + lr) * 32 + ((quad ^ rsw) << 3)];
#pragma unroll
    for (int ni = 0; ni < 4; ++ni)
      bh[ni] = *(const half8*)&Bs[cur][(wn + ni * 16 + lr) * 32 + ((quad ^ rsw) << 3)];
    __builtin_amdgcn_s_setprio(1);
#pragma unroll
    for (int mi = 0; mi < 4; ++mi)
#pragma unroll
      for (int ni = 0; ni < 4; ++ni)
        acc[mi][ni] = __builtin_amdgcn_mfma_f32_16x16x32_f16(ah[mi], bh[ni], acc[mi][ni], 0, 0, 0);
    __builtin_amdgcn_s_setprio(0);
    cur = (cur == 2) ? 0 : cur + 1;
  }

  int om = (p.dual && job) ? p.outModeB : p.outMode;
  _Float16* c16 = (p.dual && job) ? p.C16b : p.C16;
  long long osR = (p.dual && job) ? p.cOsRb : p.cOsR;
  long long osC = (p.dual && job) ? p.cOsCb : p.cOsC;
  float* c32 = p.C32 + (p.nsplit > 1 ? (long long)ks * p.partStride : 0);
  long long cOff = (long long)bidx * p.cSB + (long long)h * p.cSH;
#pragma unroll
  for (int mi = 0; mi < 4; ++mi)
#pragma unroll
    for (int ni = 0; ni < 4; ++ni) {
      int row = m0 + wm + mi * 16 + quad * 4;
      int col = n0 + wn + ni * 16 + lr;
#pragma unroll
      for (int r = 0; r < 4; ++r) {
        float val = acc[mi][ni][r];
        long long idx = cOff + (long long)(row + r) * osR + (long long)col * osC;
        if (om == 1) c32[idx] = val;
        else c16[idx] = (_Float16)val;
      }
    }
}

__global__ __launch_bounds__(256) void gemm_nt(GemmParams p) {
  int id = blockIdx.x;
  if (p.swz) {
    int q = (int)gridDim.x >> 3;
    id = (id & 7) * q + (id >> 3);
  }
  int bx = id % p.gx;
  int r = id / p.gx;
  gemm_body(p, bx, r % p.gy, r / p.gy);
}

__global__ __launch_bounds__(256) void gemm_pair(GemmParams a, GemmParams b, int na) {
  int id = blockIdx.x;
  if (id < na) {
    int bx = id % a.gx;
    int r = id / a.gx;
    gemm_body(a, bx, r % a.gy, r / a.gy);
  } else {
    int j = id - na;
    int bx = j % b.gx;
    int r = j / b.gx;
    gemm_body(b, bx, r % b.gy, r / b.gy);
  }
}

// ---------------------------------------------------------------- host
extern "C" void kernel_launch(void* const* d_in, const int* in_sizes, int n_in,
                              void* d_out, int out_size, void* d_ws, size_t ws_size,
                              hipStream_t stream) {
  const float* hidden = (const float*)d_in[0];   // (2,1024,2048)
  const float* memory = (const float*)d_in[1];   // (2048,1024)
  const float* Wq = (const float*)d_in[2];       // (1024,2048)
  const float* Wk = (const float*)d_in[3];       // (1024,1024)
  const float* Wv = (const float*)d_in[4];       // (1024,1024)
  const float* Wo = (const float*)d_in[5];       // (2048,1024)
  const float* log_beta = (const float*)d_in[6]; // (8,)
  const float* g_state = (const float*)d_in[7];
  const float* b_state = (const float*)d_in[8];
  const float* g_mem = (const float*)d_in[9];
  const float* b_mem = (const float*)d_in[10];

  char* w = (char*)d_ws;
  auto alloc = [&](size_t bytes) {
    char* r = w;
    w += (bytes + 255) & ~(size_t)255;
    return r;
  };
  _Float16* wq16 = (_Float16*)alloc(2097152 * 2);
  _Float16* wk16 = (_Float16*)alloc(1048576 * 2);
  _Float16* wv16 = (_Float16*)alloc(1048576 * 2);
  _Float16* wo16 = (_Float16*)alloc(2097152 * 2);
  _Float16* lnh16 = (_Float16*)alloc(4194304 * 2);
  _Float16* mn16 = (_Float16*)alloc(2097152 * 2);
  _Float16* kph = (_Float16*)alloc(2097152 * 2);   // K proj (n, h*128+d)
  _Float16* vt16 = (_Float16*)alloc(2097152 * 2);  // V^T (h*128+d, n)
  _Float16* xih = (_Float16*)alloc(2097152 * 2);   // xi (b*S+s, h*128+d)
  float* parts = (float*)alloc((size_t)2 * 2097152 * 4);  // Q split-K partials

  ln_all<<<4096, 256, 0, stream>>>(hidden, memory, g_state, b_state, g_mem, b_mem, lnh16, mn16);
  cast_all<<<6144, 256, 0, stream>>>(Wq, wq16, Wk, wk16, Wv, wv16, Wo, wo16);

  // Q = ln(hidden) @ Wq^T (split-K=2) + K/V projections (dual) in ONE launch
  {
    GemmParams pq{};
    pq.A = lnh16; pq.lda = 2048;
    pq.B = wq16; pq.ldb = 2048;
    pq.K = 2048; pq.nsplit = 2;
    pq.C32 = parts; pq.outMode = 1; pq.partStride = 2097152;
    pq.cOsR = 1024; pq.cOsC = 1;
    pq.gx = 16; pq.gy = 16;  // 256 blocks

    GemmParams pkv{};
    pkv.A = mn16; pkv.lda = 1024;
    pkv.B = wk16; pkv.B2 = wv16; pkv.ldb = 1024;
    pkv.K = 1024; pkv.dual = 1;
    pkv.C16 = kph; pkv.outMode = 0; pkv.cOsR = 1024; pkv.cOsC = 1;
    pkv.C16b = vt16; pkv.outModeB = 0; pkv.cOsRb = 1; pkv.cOsCb = 2048;
    pkv.gx = 8; pkv.gy = 16;  // gz=2 -> 256 blocks

    gemm_pair<<<512, 256, 0, stream>>>(pq, pkv, 256);
    reduce_split<<<2048, 256, 0, stream>>>(parts, 2, 2097152, xih, 2097152);
  }

  // 3 Hopfield steps, fully fused per step (scores never leave the CU)
  for (int step = 0; step < 3; ++step)
    fused_step<<<1024, 256, 0, stream>>>(xih, kph, vt16, log_beta, xih);

  // out = xi @ Wo^T  (fp32 out)
  {
    GemmParams p{};
    p.A = xih; p.lda = 1024;
    p.B = wo16; p.ldb = 1024;
    p.K = 1024;
    p.C32 = (float*)d_out; p.outMode = 1;
    p.cOsR = 2048; p.cOsC = 1;
    p.gx = 16; p.gy = 16; p.swz = 1;  // 256 blocks
    gemm_nt<<<256, 256, 0, stream>>>(p);
  }
}